// Round 4
// baseline (942.768 us; speedup 1.0000x reference)
//
#include <hip/hip_runtime.h>
#include <stdint.h>

#define B_    16
#define C_    512
#define HEADS 16
#define NTOK  49
#define ROWS  (16*56*56)   // 50176

typedef __attribute__((ext_vector_type(8))) __bf16 bf16x8;
typedef __attribute__((ext_vector_type(4))) float  f32x4;
typedef __attribute__((ext_vector_type(8))) unsigned short u16x8;
typedef __attribute__((ext_vector_type(4))) unsigned short u16x4;

__device__ __forceinline__ unsigned short f2bf(float f) {
  union { float f; uint32_t u; } x; x.f = f;
  uint32_t r = x.u + 0x7FFFu + ((x.u >> 16) & 1u);
  return (unsigned short)(r >> 16);
}
__device__ __forceinline__ float bf2f(unsigned short u) {
  union { uint32_t u; float f; } x; x.u = ((uint32_t)u) << 16;
  return x.f;
}

// ---------------- GEMM: C = A(MxK,bf16) * Bt(NxK,bf16,row-stride ldb)^T + epilogue
// EPI 0: +bias -> bf16.  EPI 1: +bias, exact GELU -> bf16.
// EPI 2: +bias +res -> f32.  EPI 3: +res -> f32 (no bias; accumulation chunks).
// 128x128 tile, BK=32, 4 waves (2x2), global_load_lds w=16,
// T1 XCD-chunked swizzle + T4 depth-2 counted-vmcnt pipeline (3 LDS bufs,
// raw s_barrier, vmcnt(4) in steady state - loads stay in flight across
// barriers) + T5 setprio around the MFMA cluster.
template<int EPI>
__global__ __launch_bounds__(256)
void gemm_bt(const unsigned short* __restrict__ A,
             const unsigned short* __restrict__ Bt,
             const float* __restrict__ bias,
             const float* __restrict__ res,
             void* __restrict__ outp,
             int N, int K, int ldb, int nbn)
{
  __shared__ __align__(16) unsigned short As[3][128*32];
  __shared__ __align__(16) unsigned short Bs[3][128*32];

  // T1: bijective XCD-chunked remap (m204).
  const int nwg = gridDim.x;
  const int q8 = nwg >> 3, r8 = nwg & 7;
  const int xcd = blockIdx.x & 7, ixc = blockIdx.x >> 3;
  const int l = (xcd < r8 ? xcd * (q8 + 1) : r8 * (q8 + 1) + (xcd - r8) * q8) + ixc;
  const int bm = l / nbn, bn = l % nbn;

  const int tid  = threadIdx.x;
  const int wave = tid >> 6;
  const int lane = tid & 63;
  const int wr = wave >> 1, wc = wave & 1;

  const int srow = lane >> 2;        // row within 16-row staging segment
  const int sk   = (lane & 3) * 8;   // k offset within BK=32
  const unsigned short* Ag = A  + (size_t)bm * 128 * K;
  const unsigned short* Bg = Bt + (size_t)bn * 128 * ldb;

  f32x4 acc[4][4] = {};
  const int fr = lane & 15;          // fragment row/col (A row, B col)
  const int kb = (lane >> 4) * 8;    // fragment k base

  const int seg0 = wave * 2, seg1 = wave * 2 + 1;
  const int row0 = seg0 * 16 + srow, row1 = seg1 * 16 + srow;

  auto STAGE = [&](int buf, int t) {   // 4 global_load_lds (vmcnt +4)
    const int k0 = t << 5;
    __builtin_amdgcn_global_load_lds(
      (const __attribute__((address_space(1))) void*)(Ag + (size_t)row0 * K + (k0 + sk)),
      (__attribute__((address_space(3))) void*)(&As[buf][seg0 * 512]), 16, 0, 0);
    __builtin_amdgcn_global_load_lds(
      (const __attribute__((address_space(1))) void*)(Ag + (size_t)row1 * K + (k0 + sk)),
      (__attribute__((address_space(3))) void*)(&As[buf][seg1 * 512]), 16, 0, 0);
    __builtin_amdgcn_global_load_lds(
      (const __attribute__((address_space(1))) void*)(Bg + (size_t)row0 * ldb + (k0 + sk)),
      (__attribute__((address_space(3))) void*)(&Bs[buf][seg0 * 512]), 16, 0, 0);
    __builtin_amdgcn_global_load_lds(
      (const __attribute__((address_space(1))) void*)(Bg + (size_t)row1 * ldb + (k0 + sk)),
      (__attribute__((address_space(3))) void*)(&Bs[buf][seg1 * 512]), 16, 0, 0);
  };

  const int nt = K >> 5;               // K in {512,2048} -> nt in {16,64}
  STAGE(0, 0);
  STAGE(1, 1);
  int cur = 0;
  for (int t = 0; t < nt; ++t) {
    // RAW: own oldest 4 loads (buf cur) done; barrier -> all waves' done.
    if (t == nt - 1) asm volatile("s_waitcnt vmcnt(0)" ::: "memory");
    else             asm volatile("s_waitcnt vmcnt(4)" ::: "memory");
    __builtin_amdgcn_s_barrier();

    bf16x8 a[4], b[4];
    #pragma unroll
    for (int m = 0; m < 4; ++m)
      a[m] = *(const bf16x8*)&As[cur][(wr * 64 + m * 16 + fr) * 32 + kb];
    #pragma unroll
    for (int n = 0; n < 4; ++n)
      b[n] = *(const bf16x8*)&Bs[cur][(wc * 64 + n * 16 + fr) * 32 + kb];
    __builtin_amdgcn_s_setprio(1);
    #pragma unroll
    for (int m = 0; m < 4; ++m)
      #pragma unroll
      for (int n = 0; n < 4; ++n)
        acc[m][n] = __builtin_amdgcn_mfma_f32_16x16x32_bf16(a[m], b[n], acc[m][n], 0, 0, 0);
    __builtin_amdgcn_s_setprio(0);

    // WAR: all LDS reads retired before any wave restages this region (t+2).
    asm volatile("s_waitcnt lgkmcnt(0)" ::: "memory");
    __builtin_amdgcn_s_barrier();
    if (t + 2 < nt) {
      int nb = cur + 2; if (nb >= 3) nb -= 3;
      STAGE(nb, t + 2);
    }
    cur = (cur == 2) ? 0 : cur + 1;
  }

  const int rq = lane >> 4;          // C/D: row=(lane>>4)*4+r, col=lane&15
  #pragma unroll
  for (int m = 0; m < 4; ++m) {
    #pragma unroll
    for (int n = 0; n < 4; ++n) {
      const int gcol = bn * 128 + wc * 64 + n * 16 + fr;
      const float bv = (EPI == 3) ? 0.f : bias[gcol];
      #pragma unroll
      for (int r = 0; r < 4; ++r) {
        const int grow = bm * 128 + wr * 64 + m * 16 + rq * 4 + r;
        const size_t off = (size_t)grow * N + gcol;
        float v = acc[m][n][r] + bv;
        if (EPI == 0) {
          ((unsigned short*)outp)[off] = f2bf(v);
        } else if (EPI == 1) {
          v = 0.5f * v * (1.0f + erff(v * 0.70710678118654752f));
          ((unsigned short*)outp)[off] = f2bf(v);
        } else {
          ((float*)outp)[off] = v + res[off];
        }
      }
    }
  }
}

// ---------------- LayerNorm (f32 in) -> bf16 out. 1 wave per row of 512.
__global__ __launch_bounds__(256)
void ln_bf16(const float* __restrict__ x, const float* __restrict__ w,
             const float* __restrict__ b, unsigned short* __restrict__ out)
{
  const int row  = blockIdx.x * 4 + (threadIdx.x >> 6);
  const int lane = threadIdx.x & 63;
  const float4* xr = (const float4*)(x + (size_t)row * C_);
  const float4 u = xr[lane * 2];
  const float4 v = xr[lane * 2 + 1];
  const float vals[8] = {u.x,u.y,u.z,u.w,v.x,v.y,v.z,v.w};
  float s = 0.f, s2 = 0.f;
  #pragma unroll
  for (int j = 0; j < 8; ++j) { s += vals[j]; s2 += vals[j]*vals[j]; }
  #pragma unroll
  for (int off = 1; off < 64; off <<= 1) {
    s  += __shfl_xor(s,  off);
    s2 += __shfl_xor(s2, off);
  }
  const float mean = s * (1.0f/512.0f);
  const float rstd = rsqrtf(s2 * (1.0f/512.0f) - mean*mean + 1e-5f);
  u16x8 o;
  #pragma unroll
  for (int j = 0; j < 8; ++j) {
    const int col = lane * 8 + j;
    o[j] = f2bf((vals[j] - mean) * rstd * w[col] + b[col]);
  }
  *(u16x8*)&out[(size_t)row * C_ + lane * 8] = o;
}

// ---------------- Window attention: 1 wave per (window, head).
// qkv holds a CHUNK starting at image i0 (local rows); outb is the FULL buffer
// in original (B,H*W) row order (window gather/scatter via index math).
__global__ __launch_bounds__(64)
void attn_win(const unsigned short* __restrict__ qkv,
              const float* __restrict__ biasMat,
              unsigned short* __restrict__ outb, int i0)
{
  const int head = blockIdx.x & 15;
  const int winl = blockIdx.x >> 4;          // local window within chunk
  const int bbl = winl >> 6, wy = (winl >> 3) & 7, wx = winl & 7;
  __shared__ float Ks[NTOK*32];
  __shared__ float Vs[NTOK*32];
  __shared__ float Bsh[NTOK*NTOK];
  const int lane = threadIdx.x;
  for (int i = lane; i < NTOK*NTOK; i += 64)
    Bsh[i] = biasMat[head * (NTOK*NTOK) + i];
  float q[32];
  size_t gl = 0, gg = 0;
  if (lane < NTOK) {
    const int r = lane / 7, c = lane % 7;
    gl = (size_t)bbl * 3136 + (size_t)((wy*7 + r) * 56 + (wx*7 + c));
    gg = gl + (size_t)i0 * 3136;
    const unsigned short* qp = qkv + gl * 1536 + head * 32;
    #pragma unroll
    for (int d = 0; d < 32; d += 4) {
      const u16x4 qv = *(const u16x4*)&qp[d];
      const u16x4 kv = *(const u16x4*)&qp[512 + d];
      const u16x4 vv = *(const u16x4*)&qp[1024 + d];
      #pragma unroll
      for (int e = 0; e < 4; ++e) {
        q[d+e] = bf2f(qv[e]);
        Ks[lane*32 + d + e] = bf2f(kv[e]);
        Vs[lane*32 + d + e] = bf2f(vv[e]);
      }
    }
  }
  __syncthreads();
  if (lane < NTOK) {
    float s[NTOK];
    float mx = -1e30f;
    for (int j = 0; j < NTOK; ++j) {
      float dot = 0.f;
      #pragma unroll
      for (int d = 0; d < 32; ++d) dot += q[d] * Ks[j*32 + d];  // lane-uniform LDS addr: broadcast
      const float val = dot * 0.17677669529663687f + Bsh[lane*NTOK + j];
      s[j] = val;
      mx = fmaxf(mx, val);
    }
    float sum = 0.f;
    for (int j = 0; j < NTOK; ++j) { s[j] = __expf(s[j] - mx); sum += s[j]; }
    const float inv = 1.0f / sum;
    float o[32];
    #pragma unroll
    for (int d = 0; d < 32; ++d) o[d] = 0.f;
    for (int j = 0; j < NTOK; ++j) {
      const float p = s[j] * inv;
      #pragma unroll
      for (int d = 0; d < 32; ++d) o[d] += p * Vs[j*32 + d];    // broadcast
    }
    unsigned short* op = outb + gg * 512 + head * 32;           // window-reverse scatter
    #pragma unroll
    for (int d = 0; d < 32; d += 4) {
      u16x4 ov;
      #pragma unroll
      for (int e = 0; e < 4; ++e) ov[e] = f2bf(o[d+e]);
      *(u16x4*)&op[d] = ov;
    }
  }
}

// ---------------- small prep kernels
__global__ void build_bias(const float* __restrict__ table, const int* __restrict__ idx,
                           float* __restrict__ biasMat)
{
  const int i = blockIdx.x * 256 + threadIdx.x;
  if (i >= HEADS * NTOK * NTOK) return;
  const int h  = i / (NTOK*NTOK);
  const int ij = i - h * (NTOK*NTOK);
  biasMat[i] = table[idx[ij] * HEADS + h];
}

__global__ void conv_bf16(const float* __restrict__ in, unsigned short* __restrict__ out, int n4)
{
  const int i = blockIdx.x * 256 + threadIdx.x;
  if (i >= n4) return;
  const float4 v = ((const float4*)in)[i];
  u16x4 o; o[0]=f2bf(v.x); o[1]=f2bf(v.y); o[2]=f2bf(v.z); o[3]=f2bf(v.w);
  ((u16x4*)out)[i] = o;
}

extern "C" void kernel_launch(void* const* d_in, const int* in_sizes, int n_in,
                              void* d_out, int out_size, void* d_ws, size_t ws_size,
                              hipStream_t stream)
{
  const float* x     = (const float*)d_in[0];
  const float* n1w   = (const float*)d_in[1];
  const float* n1b   = (const float*)d_in[2];
  const float* qkvw  = (const float*)d_in[3];
  const float* qkvb  = (const float*)d_in[4];
  const float* projw = (const float*)d_in[5];
  const float* projb = (const float*)d_in[6];
  const float* rbt   = (const float*)d_in[7];
  const float* n2w   = (const float*)d_in[8];
  const float* n2b   = (const float*)d_in[9];
  const float* fc1w  = (const float*)d_in[10];
  const float* fc1b  = (const float*)d_in[11];
  const float* fc2w  = (const float*)d_in[12];
  const float* fc2b  = (const float*)d_in[13];
  const int*   rpi   = (const int*)d_in[14];
  float* out = (float*)d_out;

  // ---- adaptive workspace layout: fixed small region + bufX + reusable R ----
  char* p = (char*)d_ws;
  auto alloc = [&](size_t bytes) -> char* {
    char* q = p; p += (bytes + 255) & ~(size_t)255; return q;
  };
  unsigned short* wqB  = (unsigned short*)alloc((size_t)1536 * 512 * 2);
  unsigned short* wpB  = (unsigned short*)alloc((size_t)512  * 512 * 2);
  unsigned short* w1B  = (unsigned short*)alloc((size_t)2048 * 512 * 2);
  unsigned short* w2B  = (unsigned short*)alloc((size_t)512  * 2048 * 2);
  float* biasMat       = (float*)alloc((size_t)HEADS * NTOK * NTOK * 4);
  unsigned short* bufX = (unsigned short*)alloc((size_t)ROWS * 512 * 2);
  const size_t used = (size_t)(p - (char*)d_ws);
  const size_t Rbytes = (ws_size > used) ? ws_size - used : 0;
  unsigned short* R = (unsigned short*)p;

  // qkv chunk: ic images (ic*3136 rows, must be mult of 128 -> ic even)
  int ic = 0;
  for (int c = 16; c >= 2; c >>= 1)
    if ((size_t)c * 3136 * 1536 * 2 <= Rbytes) { ic = c; break; }
  // mlp hidden chunk
  int hc = 0;
  for (int c = 2048; c >= 128; c >>= 1)
    if ((size_t)ROWS * c * 2 <= Rbytes) { hc = c; break; }
  if (ic == 0 || hc == 0) return;  // ws too small: clean failure, not a fault

  conv_bf16<<<(1536*512/4 + 255)/256, 256, 0, stream>>>(qkvw, wqB, 1536*512/4);
  conv_bf16<<<(512*512/4  + 255)/256, 256, 0, stream>>>(projw, wpB, 512*512/4);
  conv_bf16<<<(2048*512/4 + 255)/256, 256, 0, stream>>>(fc1w, w1B, 2048*512/4);
  conv_bf16<<<(512*2048/4 + 255)/256, 256, 0, stream>>>(fc2w, w2B, 512*2048/4);
  build_bias<<<(HEADS*NTOK*NTOK + 255)/256, 256, 0, stream>>>(rbt, rpi, biasMat);

  // LN1 -> bf16
  ln_bf16<<<ROWS/4, 256, 0, stream>>>(x, n1w, n1b, bufX);

  // QKV GEMM + window attention, chunked over images.
  for (int i0 = 0; i0 < B_; i0 += ic) {
    const int nbm = ic * 3136 / 128, nbn = 12;
    gemm_bt<0><<<nbm * nbn, 256, 0, stream>>>(
        bufX + (size_t)i0*3136*512, wqB, qkvb, nullptr, R, 1536, 512, 512, nbn);
    attn_win<<<ic*64*16, 64, 0, stream>>>(R, biasMat, bufX, i0);
  }

  // proj GEMM + residual(x) -> d_out (f32)  [= x1]
  gemm_bt<2><<<(ROWS/128) * 4, 256, 0, stream>>>(
      bufX, wpB, projb, x, out, 512, 512, 512, 4);

  // LN2 -> bf16
  ln_bf16<<<ROWS/4, 256, 0, stream>>>(out, n2w, n2b, bufX);

  // MLP, chunked over hidden dim. FC2 accumulates into out (bias in chunk 0).
  for (int h0 = 0; h0 < 2048; h0 += hc) {
    gemm_bt<1><<<(ROWS/128) * (hc/128), 256, 0, stream>>>(
        bufX, w1B + (size_t)h0*512, fc1b + h0, nullptr, R, hc, 512, 512, hc/128);
    if (h0 == 0)
      gemm_bt<2><<<(ROWS/128) * 4, 256, 0, stream>>>(
          R, w2B + h0, fc2b, out, out, 512, hc, 2048, 4);
    else
      gemm_bt<3><<<(ROWS/128) * 4, 256, 0, stream>>>(
          R, w2B + h0, nullptr, out, out, 512, hc, 2048, 4);
  }
}

// Round 5
// 867.996 us; speedup vs baseline: 1.0861x; 1.0861x over previous
//
#include <hip/hip_runtime.h>
#include <stdint.h>

#define B_    16
#define C_    512
#define HEADS 16
#define NTOK  49
#define ROWS  (16*56*56)   // 50176

typedef __attribute__((ext_vector_type(8))) __bf16 bf16x8;
typedef __attribute__((ext_vector_type(4))) float  f32x4;
typedef __attribute__((ext_vector_type(8))) unsigned short u16x8;
typedef __attribute__((ext_vector_type(4))) unsigned short u16x4;

__device__ __forceinline__ unsigned short f2bf(float f) {
  union { float f; uint32_t u; } x; x.f = f;
  uint32_t r = x.u + 0x7FFFu + ((x.u >> 16) & 1u);
  return (unsigned short)(r >> 16);
}
__device__ __forceinline__ float bf2f(unsigned short u) {
  union { uint32_t u; float f; } x; x.u = ((uint32_t)u) << 16;
  return x.f;
}

// ---------------- GEMM: C = A(MxK,bf16) * Bt(NxK,bf16,row-stride ldb)^T + epilogue
// EPI 0: +bias -> bf16.  EPI 1: +bias, exact GELU -> bf16.
// EPI 2: +bias +res -> f32.  EPI 3: +res -> f32 (no bias; accumulation chunks).
//
// 256x256 tile, BK=64, 8 waves (2M x 4N), per-wave output 128x64.
// LDS 128 KiB: A[2][256][64] + B[2][256][64] bf16, double-buffered.
// T1 XCD-chunked bijective swizzle; T2 LDS XOR-swizzle done as
// pre-swizzled GLOBAL source (linear global_load_lds dest) + XOR on the
// ds_read address (rule 21; involution g = s ^ (row&7) on 16B k-groups);
// T4 counted vmcnt(8) (one full tile = 16 loads/thread... 8 per matrix pair
// kept in flight) - never 0 in the main loop; T5 setprio around MFMA.
// Depth-1 prefetch suffices: per-iter matrix-pipe time (~2480 cyc/SIMD)
// >> HBM latency (~900 cyc).
template<int EPI>
__global__ __launch_bounds__(512, 2)
void gemm_bt(const unsigned short* __restrict__ A,
             const unsigned short* __restrict__ Bt,
             const float* __restrict__ bias,
             const float* __restrict__ res,
             void* __restrict__ outp,
             int N, int K, int ldb, int nbn)
{
  __shared__ __align__(16) unsigned short As[2][256*64];
  __shared__ __align__(16) unsigned short Bs[2][256*64];

  // T1: bijective XCD-chunked remap (m204).
  const int nwg = gridDim.x;
  const int q8 = nwg >> 3, r8 = nwg & 7;
  const int xcd = blockIdx.x & 7, ixc = blockIdx.x >> 3;
  const int l = (xcd < r8 ? xcd * (q8 + 1) : r8 * (q8 + 1) + (xcd - r8) * q8) + ixc;
  const int bm = l / nbn, bn = l % nbn;

  const int tid  = threadIdx.x;
  const int wave = tid >> 6;
  const int lane = tid & 63;
  const int wr = wave >> 2, wc = wave & 3;   // 2 (M) x 4 (N) waves

  const unsigned short* Ag = A  + (size_t)bm * 256 * K;
  const unsigned short* Bg = Bt + (size_t)bn * 256 * ldb;

  f32x4 acc[8][4] = {};
  const int fr = lane & 15;          // fragment row (A row / B col within 16)
  const int kq = lane >> 4;          // k-quarter within 32 (8 bf16 groups)
  const int sx = fr & 7;             // read-side XOR key (row&7 == fr&7)

  // Staging: slot = tid + l*512 covers 2048 16B-slots = one 256x64 bf16 tile.
  // LDS linear at slot*16B; global source k-group g = (slot&7) ^ (row&7).
  auto STAGE = [&](int buf, int t) {   // 8 global_load_lds per thread
    const int k0 = t << 6;
    #pragma unroll
    for (int li = 0; li < 4; ++li) {
      const int slot = tid + li * 512;
      const int r = slot >> 3;
      const int g = (slot & 7) ^ (r & 7);
      __builtin_amdgcn_global_load_lds(
        (const __attribute__((address_space(1))) void*)(Ag + (size_t)r * K + k0 + g * 8),
        (__attribute__((address_space(3))) void*)(&As[buf][(li * 512 + wave * 64) * 8]), 16, 0, 0);
    }
    #pragma unroll
    for (int li = 0; li < 4; ++li) {
      const int slot = tid + li * 512;
      const int r = slot >> 3;
      const int g = (slot & 7) ^ (r & 7);
      __builtin_amdgcn_global_load_lds(
        (const __attribute__((address_space(1))) void*)(Bg + (size_t)r * ldb + k0 + g * 8),
        (__attribute__((address_space(3))) void*)(&Bs[buf][(li * 512 + wave * 64) * 8]), 16, 0, 0);
    }
  };

  const int nt = K >> 6;               // K in {512,2048} -> nt in {8,32}
  STAGE(0, 0);
  for (int t = 0; t < nt; ++t) {
    const int c = t & 1;
    if (t + 1 < nt) {
      STAGE(c ^ 1, t + 1);             // issue next tile BEFORE waiting
      asm volatile("s_waitcnt vmcnt(8)" ::: "memory");   // own tile-t loads done
    } else {
      asm volatile("s_waitcnt vmcnt(0)" ::: "memory");
    }
    __builtin_amdgcn_s_barrier();      // all waves' tile-t loads done

    #pragma unroll
    for (int ks = 0; ks < 2; ++ks) {   // two K=32 slots within BK=64
      bf16x8 a[8], b[4];
      #pragma unroll
      for (int m = 0; m < 8; ++m)
        a[m] = *(const bf16x8*)&As[c][(wr * 128 + m * 16 + fr) * 64
                                      + (((ks * 4 + kq) ^ sx) * 8)];
      #pragma unroll
      for (int n = 0; n < 4; ++n)
        b[n] = *(const bf16x8*)&Bs[c][(wc * 64 + n * 16 + fr) * 64
                                      + (((ks * 4 + kq) ^ sx) * 8)];
      __builtin_amdgcn_s_setprio(1);
      #pragma unroll
      for (int m = 0; m < 8; ++m)
        #pragma unroll
        for (int n = 0; n < 4; ++n)
          acc[m][n] = __builtin_amdgcn_mfma_f32_16x16x32_bf16(a[m], b[n], acc[m][n], 0, 0, 0);
      __builtin_amdgcn_s_setprio(0);
    }

    // WAR fence: all LDS reads of buf c retired before next iter restages c^1
    // (c^1 already safe) and before iter t+2 overwrites buf c.
    asm volatile("s_waitcnt lgkmcnt(0)" ::: "memory");
    __builtin_amdgcn_s_barrier();
  }

  const int rq = lane >> 4;          // C/D: row=(lane>>4)*4+r, col=lane&15
  #pragma unroll
  for (int m = 0; m < 8; ++m) {
    #pragma unroll
    for (int n = 0; n < 4; ++n) {
      const int gcol = bn * 256 + wc * 64 + n * 16 + fr;
      const float bv = (EPI == 3) ? 0.f : bias[gcol];
      #pragma unroll
      for (int r = 0; r < 4; ++r) {
        const int grow = bm * 256 + wr * 128 + m * 16 + rq * 4 + r;
        const size_t off = (size_t)grow * N + gcol;
        float v = acc[m][n][r] + bv;
        if (EPI == 0) {
          ((unsigned short*)outp)[off] = f2bf(v);
        } else if (EPI == 1) {
          v = 0.5f * v * (1.0f + erff(v * 0.70710678118654752f));
          ((unsigned short*)outp)[off] = f2bf(v);
        } else {
          ((float*)outp)[off] = v + res[off];
        }
      }
    }
  }
}

// ---------------- LayerNorm (f32 in) -> bf16 out. 1 wave per row of 512.
__global__ __launch_bounds__(256)
void ln_bf16(const float* __restrict__ x, const float* __restrict__ w,
             const float* __restrict__ b, unsigned short* __restrict__ out)
{
  const int row  = blockIdx.x * 4 + (threadIdx.x >> 6);
  const int lane = threadIdx.x & 63;
  const float4* xr = (const float4*)(x + (size_t)row * C_);
  const float4 u = xr[lane * 2];
  const float4 v = xr[lane * 2 + 1];
  const float vals[8] = {u.x,u.y,u.z,u.w,v.x,v.y,v.z,v.w};
  float s = 0.f, s2 = 0.f;
  #pragma unroll
  for (int j = 0; j < 8; ++j) { s += vals[j]; s2 += vals[j]*vals[j]; }
  #pragma unroll
  for (int off = 1; off < 64; off <<= 1) {
    s  += __shfl_xor(s,  off);
    s2 += __shfl_xor(s2, off);
  }
  const float mean = s * (1.0f/512.0f);
  const float rstd = rsqrtf(s2 * (1.0f/512.0f) - mean*mean + 1e-5f);
  u16x8 o;
  #pragma unroll
  for (int j = 0; j < 8; ++j) {
    const int col = lane * 8 + j;
    o[j] = f2bf((vals[j] - mean) * rstd * w[col] + b[col]);
  }
  *(u16x8*)&out[(size_t)row * C_ + lane * 8] = o;
}

// ---------------- Window attention: 1 wave per (window, head).
__global__ __launch_bounds__(64)
void attn_win(const unsigned short* __restrict__ qkv,
              const float* __restrict__ biasMat,
              unsigned short* __restrict__ outb, int i0)
{
  const int head = blockIdx.x & 15;
  const int winl = blockIdx.x >> 4;          // local window within chunk
  const int bbl = winl >> 6, wy = (winl >> 3) & 7, wx = winl & 7;
  __shared__ float Ks[NTOK*32];
  __shared__ float Vs[NTOK*32];
  __shared__ float Bsh[NTOK*NTOK];
  const int lane = threadIdx.x;
  for (int i = lane; i < NTOK*NTOK; i += 64)
    Bsh[i] = biasMat[head * (NTOK*NTOK) + i];
  float q[32];
  size_t gl = 0, gg = 0;
  if (lane < NTOK) {
    const int r = lane / 7, c = lane % 7;
    gl = (size_t)bbl * 3136 + (size_t)((wy*7 + r) * 56 + (wx*7 + c));
    gg = gl + (size_t)i0 * 3136;
    const unsigned short* qp = qkv + gl * 1536 + head * 32;
    #pragma unroll
    for (int d = 0; d < 32; d += 4) {
      const u16x4 qv = *(const u16x4*)&qp[d];
      const u16x4 kv = *(const u16x4*)&qp[512 + d];
      const u16x4 vv = *(const u16x4*)&qp[1024 + d];
      #pragma unroll
      for (int e = 0; e < 4; ++e) {
        q[d+e] = bf2f(qv[e]);
        Ks[lane*32 + d + e] = bf2f(kv[e]);
        Vs[lane*32 + d + e] = bf2f(vv[e]);
      }
    }
  }
  __syncthreads();
  if (lane < NTOK) {
    float s[NTOK];
    float mx = -1e30f;
    for (int j = 0; j < NTOK; ++j) {
      float dot = 0.f;
      #pragma unroll
      for (int d = 0; d < 32; ++d) dot += q[d] * Ks[j*32 + d];
      const float val = dot * 0.17677669529663687f + Bsh[lane*NTOK + j];
      s[j] = val;
      mx = fmaxf(mx, val);
    }
    float sum = 0.f;
    for (int j = 0; j < NTOK; ++j) { s[j] = __expf(s[j] - mx); sum += s[j]; }
    const float inv = 1.0f / sum;
    float o[32];
    #pragma unroll
    for (int d = 0; d < 32; ++d) o[d] = 0.f;
    for (int j = 0; j < NTOK; ++j) {
      const float p = s[j] * inv;
      #pragma unroll
      for (int d = 0; d < 32; ++d) o[d] += p * Vs[j*32 + d];
    }
    unsigned short* op = outb + gg * 512 + head * 32;
    #pragma unroll
    for (int d = 0; d < 32; d += 4) {
      u16x4 ov;
      #pragma unroll
      for (int e = 0; e < 4; ++e) ov[e] = f2bf(o[d+e]);
      *(u16x4*)&op[d] = ov;
    }
  }
}

// ---------------- small prep kernels
__global__ void build_bias(const float* __restrict__ table, const int* __restrict__ idx,
                           float* __restrict__ biasMat)
{
  const int i = blockIdx.x * 256 + threadIdx.x;
  if (i >= HEADS * NTOK * NTOK) return;
  const int h  = i / (NTOK*NTOK);
  const int ij = i - h * (NTOK*NTOK);
  biasMat[i] = table[idx[ij] * HEADS + h];
}

__global__ void conv_bf16(const float* __restrict__ in, unsigned short* __restrict__ out, int n4)
{
  const int i = blockIdx.x * 256 + threadIdx.x;
  if (i >= n4) return;
  const float4 v = ((const float4*)in)[i];
  u16x4 o; o[0]=f2bf(v.x); o[1]=f2bf(v.y); o[2]=f2bf(v.z); o[3]=f2bf(v.w);
  ((u16x4*)out)[i] = o;
}

extern "C" void kernel_launch(void* const* d_in, const int* in_sizes, int n_in,
                              void* d_out, int out_size, void* d_ws, size_t ws_size,
                              hipStream_t stream)
{
  const float* x     = (const float*)d_in[0];
  const float* n1w   = (const float*)d_in[1];
  const float* n1b   = (const float*)d_in[2];
  const float* qkvw  = (const float*)d_in[3];
  const float* qkvb  = (const float*)d_in[4];
  const float* projw = (const float*)d_in[5];
  const float* projb = (const float*)d_in[6];
  const float* rbt   = (const float*)d_in[7];
  const float* n2w   = (const float*)d_in[8];
  const float* n2b   = (const float*)d_in[9];
  const float* fc1w  = (const float*)d_in[10];
  const float* fc1b  = (const float*)d_in[11];
  const float* fc2w  = (const float*)d_in[12];
  const float* fc2b  = (const float*)d_in[13];
  const int*   rpi   = (const int*)d_in[14];
  float* out = (float*)d_out;

  // ---- adaptive workspace layout: fixed small region + bufX + reusable R ----
  char* p = (char*)d_ws;
  auto alloc = [&](size_t bytes) -> char* {
    char* q = p; p += (bytes + 255) & ~(size_t)255; return q;
  };
  unsigned short* wqB  = (unsigned short*)alloc((size_t)1536 * 512 * 2);
  unsigned short* wpB  = (unsigned short*)alloc((size_t)512  * 512 * 2);
  unsigned short* w1B  = (unsigned short*)alloc((size_t)2048 * 512 * 2);
  unsigned short* w2B  = (unsigned short*)alloc((size_t)512  * 2048 * 2);
  float* biasMat       = (float*)alloc((size_t)HEADS * NTOK * NTOK * 4);
  unsigned short* bufX = (unsigned short*)alloc((size_t)ROWS * 512 * 2);
  const size_t used = (size_t)(p - (char*)d_ws);
  const size_t Rbytes = (ws_size > used) ? ws_size - used : 0;
  unsigned short* R = (unsigned short*)p;

  // qkv chunk: ic images; ic*3136 rows must be a multiple of 256 -> ic in {16,8,4}
  int ic = 0;
  for (int c = 16; c >= 4; c >>= 1)
    if ((size_t)c * 3136 * 1536 * 2 <= Rbytes) { ic = c; break; }
  // mlp hidden chunk (N of FC1 = hc must be multiple of 256)
  int hc = 0;
  for (int c = 2048; c >= 256; c >>= 1)
    if ((size_t)ROWS * c * 2 <= Rbytes) { hc = c; break; }
  if (ic == 0 || hc == 0) return;  // ws too small: clean failure, not a fault

  conv_bf16<<<(1536*512/4 + 255)/256, 256, 0, stream>>>(qkvw, wqB, 1536*512/4);
  conv_bf16<<<(512*512/4  + 255)/256, 256, 0, stream>>>(projw, wpB, 512*512/4);
  conv_bf16<<<(2048*512/4 + 255)/256, 256, 0, stream>>>(fc1w, w1B, 2048*512/4);
  conv_bf16<<<(512*2048/4 + 255)/256, 256, 0, stream>>>(fc2w, w2B, 512*2048/4);
  build_bias<<<(HEADS*NTOK*NTOK + 255)/256, 256, 0, stream>>>(rbt, rpi, biasMat);

  // LN1 -> bf16
  ln_bf16<<<ROWS/4, 256, 0, stream>>>(x, n1w, n1b, bufX);

  // QKV GEMM + window attention, chunked over images.
  for (int i0 = 0; i0 < B_; i0 += ic) {
    const int nbm = ic * 3136 / 256, nbn = 6;
    gemm_bt<0><<<nbm * nbn, 512, 0, stream>>>(
        bufX + (size_t)i0*3136*512, wqB, qkvb, nullptr, R, 1536, 512, 512, nbn);
    attn_win<<<ic*64*16, 64, 0, stream>>>(R, biasMat, bufX, i0);
  }

  // proj GEMM + residual(x) -> d_out (f32)  [= x1]
  gemm_bt<2><<<(ROWS/256) * 2, 512, 0, stream>>>(
      bufX, wpB, projb, x, out, 512, 512, 512, 2);

  // LN2 -> bf16
  ln_bf16<<<ROWS/4, 256, 0, stream>>>(out, n2w, n2b, bufX);

  // MLP, chunked over hidden dim. FC2 accumulates into out (bias in chunk 0).
  for (int h0 = 0; h0 < 2048; h0 += hc) {
    gemm_bt<1><<<(ROWS/256) * (hc/256), 512, 0, stream>>>(
        bufX, w1B + (size_t)h0*512, fc1b + h0, nullptr, R, hc, 512, 512, hc/256);
    if (h0 == 0)
      gemm_bt<2><<<(ROWS/256) * 2, 512, 0, stream>>>(
          R, w2B + h0, fc2b, out, out, 512, hc, 2048, 2);
    else
      gemm_bt<3><<<(ROWS/256) * 2, 512, 0, stream>>>(
          R, w2B + h0, nullptr, out, out, 512, hc, 2048, 2);
  }
}

// Round 6
// 861.439 us; speedup vs baseline: 1.0944x; 1.0076x over previous
//
#include <hip/hip_runtime.h>
#include <stdint.h>

#define B_    16
#define C_    512
#define HEADS 16
#define NTOK  49
#define ROWS  (16*56*56)   // 50176

typedef __attribute__((ext_vector_type(8))) __bf16 bf16x8;
typedef __attribute__((ext_vector_type(4))) float  f32x4;
typedef __attribute__((ext_vector_type(8))) unsigned short u16x8;
typedef __attribute__((ext_vector_type(4))) unsigned short u16x4;

__device__ __forceinline__ unsigned short f2bf(float f) {
  union { float f; uint32_t u; } x; x.f = f;
  uint32_t r = x.u + 0x7FFFu + ((x.u >> 16) & 1u);
  return (unsigned short)(r >> 16);
}
__device__ __forceinline__ float bf2f(unsigned short u) {
  union { uint32_t u; float f; } x; x.u = ((uint32_t)u) << 16;
  return x.f;
}

// ---------------- GEMM: C = A(MxK,bf16) * Bt(NxK,bf16,row-stride ldb)^T + epilogue
// EPI 0: +bias -> bf16.  EPI 1: +bias, exact GELU -> bf16.
// EPI 2: +bias +res -> f32.  EPI 3: +res -> f32 (no bias; accumulation chunks).
// 256x256 tile, BK=64, 8 waves (2M x 4N); T1 XCD swizzle, T2 src-side XOR
// swizzle, T4 counted vmcnt(8), T5 setprio. (unchanged from R5)
template<int EPI>
__global__ __launch_bounds__(512, 2)
void gemm_bt(const unsigned short* __restrict__ A,
             const unsigned short* __restrict__ Bt,
             const float* __restrict__ bias,
             const float* __restrict__ res,
             void* __restrict__ outp,
             int N, int K, int ldb, int nbn)
{
  __shared__ __align__(16) unsigned short As[2][256*64];
  __shared__ __align__(16) unsigned short Bs[2][256*64];

  const int nwg = gridDim.x;
  const int q8 = nwg >> 3, r8 = nwg & 7;
  const int xcd = blockIdx.x & 7, ixc = blockIdx.x >> 3;
  const int l = (xcd < r8 ? xcd * (q8 + 1) : r8 * (q8 + 1) + (xcd - r8) * q8) + ixc;
  const int bm = l / nbn, bn = l % nbn;

  const int tid  = threadIdx.x;
  const int wave = tid >> 6;
  const int lane = tid & 63;
  const int wr = wave >> 2, wc = wave & 3;   // 2 (M) x 4 (N) waves

  const unsigned short* Ag = A  + (size_t)bm * 256 * K;
  const unsigned short* Bg = Bt + (size_t)bn * 256 * ldb;

  f32x4 acc[8][4] = {};
  const int fr = lane & 15;
  const int kq = lane >> 4;
  const int sx = fr & 7;

  auto STAGE = [&](int buf, int t) {   // 8 global_load_lds per thread
    const int k0 = t << 6;
    #pragma unroll
    for (int li = 0; li < 4; ++li) {
      const int slot = tid + li * 512;
      const int r = slot >> 3;
      const int g = (slot & 7) ^ (r & 7);
      __builtin_amdgcn_global_load_lds(
        (const __attribute__((address_space(1))) void*)(Ag + (size_t)r * K + k0 + g * 8),
        (__attribute__((address_space(3))) void*)(&As[buf][(li * 512 + wave * 64) * 8]), 16, 0, 0);
    }
    #pragma unroll
    for (int li = 0; li < 4; ++li) {
      const int slot = tid + li * 512;
      const int r = slot >> 3;
      const int g = (slot & 7) ^ (r & 7);
      __builtin_amdgcn_global_load_lds(
        (const __attribute__((address_space(1))) void*)(Bg + (size_t)r * ldb + k0 + g * 8),
        (__attribute__((address_space(3))) void*)(&Bs[buf][(li * 512 + wave * 64) * 8]), 16, 0, 0);
    }
  };

  const int nt = K >> 6;
  STAGE(0, 0);
  for (int t = 0; t < nt; ++t) {
    const int c = t & 1;
    if (t + 1 < nt) {
      STAGE(c ^ 1, t + 1);
      asm volatile("s_waitcnt vmcnt(8)" ::: "memory");
    } else {
      asm volatile("s_waitcnt vmcnt(0)" ::: "memory");
    }
    __builtin_amdgcn_s_barrier();

    #pragma unroll
    for (int ks = 0; ks < 2; ++ks) {
      bf16x8 a[8], b[4];
      #pragma unroll
      for (int m = 0; m < 8; ++m)
        a[m] = *(const bf16x8*)&As[c][(wr * 128 + m * 16 + fr) * 64
                                      + (((ks * 4 + kq) ^ sx) * 8)];
      #pragma unroll
      for (int n = 0; n < 4; ++n)
        b[n] = *(const bf16x8*)&Bs[c][(wc * 64 + n * 16 + fr) * 64
                                      + (((ks * 4 + kq) ^ sx) * 8)];
      __builtin_amdgcn_s_setprio(1);
      #pragma unroll
      for (int m = 0; m < 8; ++m)
        #pragma unroll
        for (int n = 0; n < 4; ++n)
          acc[m][n] = __builtin_amdgcn_mfma_f32_16x16x32_bf16(a[m], b[n], acc[m][n], 0, 0, 0);
      __builtin_amdgcn_s_setprio(0);
    }

    asm volatile("s_waitcnt lgkmcnt(0)" ::: "memory");
    __builtin_amdgcn_s_barrier();
  }

  const int rq = lane >> 4;
  #pragma unroll
  for (int m = 0; m < 8; ++m) {
    #pragma unroll
    for (int n = 0; n < 4; ++n) {
      const int gcol = bn * 256 + wc * 64 + n * 16 + fr;
      const float bv = (EPI == 3) ? 0.f : bias[gcol];
      #pragma unroll
      for (int r = 0; r < 4; ++r) {
        const int grow = bm * 256 + wr * 128 + m * 16 + rq * 4 + r;
        const size_t off = (size_t)grow * N + gcol;
        float v = acc[m][n][r] + bv;
        if (EPI == 0) {
          ((unsigned short*)outp)[off] = f2bf(v);
        } else if (EPI == 1) {
          v = 0.5f * v * (1.0f + erff(v * 0.70710678118654752f));
          ((unsigned short*)outp)[off] = f2bf(v);
        } else {
          ((float*)outp)[off] = v + res[off];
        }
      }
    }
  }
}

// ---------------- LayerNorm (f32 in) -> bf16 out. 1 wave per row of 512.
__global__ __launch_bounds__(256)
void ln_bf16(const float* __restrict__ x, const float* __restrict__ w,
             const float* __restrict__ b, unsigned short* __restrict__ out)
{
  const int row  = blockIdx.x * 4 + (threadIdx.x >> 6);
  const int lane = threadIdx.x & 63;
  const float4* xr = (const float4*)(x + (size_t)row * C_);
  const float4 u = xr[lane * 2];
  const float4 v = xr[lane * 2 + 1];
  const float vals[8] = {u.x,u.y,u.z,u.w,v.x,v.y,v.z,v.w};
  float s = 0.f, s2 = 0.f;
  #pragma unroll
  for (int j = 0; j < 8; ++j) { s += vals[j]; s2 += vals[j]*vals[j]; }
  #pragma unroll
  for (int off = 1; off < 64; off <<= 1) {
    s  += __shfl_xor(s,  off);
    s2 += __shfl_xor(s2, off);
  }
  const float mean = s * (1.0f/512.0f);
  const float rstd = rsqrtf(s2 * (1.0f/512.0f) - mean*mean + 1e-5f);
  u16x8 o;
  #pragma unroll
  for (int j = 0; j < 8; ++j) {
    const int col = lane * 8 + j;
    o[j] = f2bf((vals[j] - mean) * rstd * w[col] + b[col]);
  }
  *(u16x8*)&out[(size_t)row * C_ + lane * 8] = o;
}

// ---------------- Window attention v2: block = (window, 8-head half).
// 512 threads = 8 waves; wave = one head. Each wave stages ITS head's K,V
// (f32) + bias (bf16) into a private LDS slice -> no cross-wave syncs.
// All heads of a window co-resident on one CU: the scattered per-head 64B
// global reads hit L1/L2 lines shared across waves -> HBM fetch ~= ideal.
__global__ __launch_bounds__(512)
void attn_win2(const unsigned short* __restrict__ qkv,
               const unsigned short* __restrict__ biasBf,
               unsigned short* __restrict__ outb, int i0)
{
  __shared__ float  Ksh[8][NTOK*32];     // 50.2 KB
  __shared__ float  Vsh[8][NTOK*32];     // 50.2 KB
  __shared__ unsigned short Bsh[8][NTOK*NTOK];  // 38.4 KB (bf16 bias)
  const int bi   = blockIdx.x;
  const int half = bi & 1, winl = bi >> 1;       // winl in [0, ic*64)
  const int bbl = winl >> 6, wy = (winl >> 3) & 7, wx = winl & 7;
  const int wave = threadIdx.x >> 6, lane = threadIdx.x & 63;
  const int head = half * 8 + wave;

  // stage bias (bf16) for this wave's head: coalesced u16 copies
  for (int i = lane; i < NTOK*NTOK; i += 64)
    Bsh[wave][i] = biasBf[head * (NTOK*NTOK) + i];

  float q[32];
  size_t gl = 0, gg = 0;
  if (lane < NTOK) {
    const int r = lane / 7, c = lane % 7;
    gl = (size_t)bbl * 3136 + (size_t)((wy*7 + r) * 56 + (wx*7 + c));
    gg = gl + (size_t)i0 * 3136;
    const unsigned short* qp = qkv + gl * 1536 + head * 32;
    #pragma unroll
    for (int d = 0; d < 32; d += 4) {
      const u16x4 qv = *(const u16x4*)&qp[d];
      const u16x4 kv = *(const u16x4*)&qp[512 + d];
      const u16x4 vv = *(const u16x4*)&qp[1024 + d];
      #pragma unroll
      for (int e = 0; e < 4; ++e) {
        q[d+e] = bf2f(qv[e]);
        Ksh[wave][lane*32 + d + e] = bf2f(kv[e]);
        Vsh[wave][lane*32 + d + e] = bf2f(vv[e]);
      }
    }
  }
  // wave-local staging only: in-wave lgkmcnt ordering suffices, no barrier.
  if (lane < NTOK) {
    float s[NTOK];
    float mx = -1e30f;
    for (int j = 0; j < NTOK; ++j) {
      float dot = 0.f;
      #pragma unroll
      for (int d = 0; d < 32; ++d) dot += q[d] * Ksh[wave][j*32 + d];  // broadcast
      const float val = dot * 0.17677669529663687f
                      + bf2f(Bsh[wave][lane*NTOK + j]);
      s[j] = val;
      mx = fmaxf(mx, val);
    }
    float sum = 0.f;
    for (int j = 0; j < NTOK; ++j) { s[j] = __expf(s[j] - mx); sum += s[j]; }
    const float inv = 1.0f / sum;
    float o[32];
    #pragma unroll
    for (int d = 0; d < 32; ++d) o[d] = 0.f;
    for (int j = 0; j < NTOK; ++j) {
      const float p = s[j] * inv;
      #pragma unroll
      for (int d = 0; d < 32; ++d) o[d] += p * Vsh[wave][j*32 + d];    // broadcast
    }
    unsigned short* op = outb + gg * 512 + head * 32;   // window-reverse scatter
    #pragma unroll
    for (int d = 0; d < 32; d += 4) {
      u16x4 ov;
      #pragma unroll
      for (int e = 0; e < 4; ++e) ov[e] = f2bf(o[d+e]);
      *(u16x4*)&op[d] = ov;
    }
  }
}

// ---------------- small prep kernels
__global__ void build_bias(const float* __restrict__ table, const int* __restrict__ idx,
                           unsigned short* __restrict__ biasBf)
{
  const int i = blockIdx.x * 256 + threadIdx.x;
  if (i >= HEADS * NTOK * NTOK) return;
  const int h  = i / (NTOK*NTOK);
  const int ij = i - h * (NTOK*NTOK);
  biasBf[i] = f2bf(table[idx[ij] * HEADS + h]);
}

__global__ void conv_bf16(const float* __restrict__ in, unsigned short* __restrict__ out, int n4)
{
  const int i = blockIdx.x * 256 + threadIdx.x;
  if (i >= n4) return;
  const float4 v = ((const float4*)in)[i];
  u16x4 o; o[0]=f2bf(v.x); o[1]=f2bf(v.y); o[2]=f2bf(v.z); o[3]=f2bf(v.w);
  ((u16x4*)out)[i] = o;
}

extern "C" void kernel_launch(void* const* d_in, const int* in_sizes, int n_in,
                              void* d_out, int out_size, void* d_ws, size_t ws_size,
                              hipStream_t stream)
{
  const float* x     = (const float*)d_in[0];
  const float* n1w   = (const float*)d_in[1];
  const float* n1b   = (const float*)d_in[2];
  const float* qkvw  = (const float*)d_in[3];
  const float* qkvb  = (const float*)d_in[4];
  const float* projw = (const float*)d_in[5];
  const float* projb = (const float*)d_in[6];
  const float* rbt   = (const float*)d_in[7];
  const float* n2w   = (const float*)d_in[8];
  const float* n2b   = (const float*)d_in[9];
  const float* fc1w  = (const float*)d_in[10];
  const float* fc1b  = (const float*)d_in[11];
  const float* fc2w  = (const float*)d_in[12];
  const float* fc2b  = (const float*)d_in[13];
  const int*   rpi   = (const int*)d_in[14];
  float* out = (float*)d_out;

  // ---- adaptive workspace layout: fixed small region + bufX + reusable R ----
  char* p = (char*)d_ws;
  auto alloc = [&](size_t bytes) -> char* {
    char* q = p; p += (bytes + 255) & ~(size_t)255; return q;
  };
  unsigned short* wqB  = (unsigned short*)alloc((size_t)1536 * 512 * 2);
  unsigned short* wpB  = (unsigned short*)alloc((size_t)512  * 512 * 2);
  unsigned short* w1B  = (unsigned short*)alloc((size_t)2048 * 512 * 2);
  unsigned short* w2B  = (unsigned short*)alloc((size_t)512  * 2048 * 2);
  unsigned short* biasBf = (unsigned short*)alloc((size_t)HEADS * NTOK * NTOK * 2);
  unsigned short* bufX = (unsigned short*)alloc((size_t)ROWS * 512 * 2);
  const size_t used = (size_t)(p - (char*)d_ws);
  const size_t Rbytes = (ws_size > used) ? ws_size - used : 0;
  unsigned short* R = (unsigned short*)p;

  // qkv chunk: ic images; ic*3136 rows must be a multiple of 256 -> ic in {16,8,4}
  int ic = 0;
  for (int c = 16; c >= 4; c >>= 1)
    if ((size_t)c * 3136 * 1536 * 2 <= Rbytes) { ic = c; break; }
  // mlp hidden chunk (N of FC1 = hc must be multiple of 256)
  int hc = 0;
  for (int c = 2048; c >= 256; c >>= 1)
    if ((size_t)ROWS * c * 2 <= Rbytes) { hc = c; break; }
  if (ic == 0 || hc == 0) return;  // ws too small: clean failure, not a fault

  conv_bf16<<<(1536*512/4 + 255)/256, 256, 0, stream>>>(qkvw, wqB, 1536*512/4);
  conv_bf16<<<(512*512/4  + 255)/256, 256, 0, stream>>>(projw, wpB, 512*512/4);
  conv_bf16<<<(2048*512/4 + 255)/256, 256, 0, stream>>>(fc1w, w1B, 2048*512/4);
  conv_bf16<<<(512*2048/4 + 255)/256, 256, 0, stream>>>(fc2w, w2B, 512*2048/4);
  build_bias<<<(HEADS*NTOK*NTOK + 255)/256, 256, 0, stream>>>(rbt, rpi, biasBf);

  // LN1 -> bf16
  ln_bf16<<<ROWS/4, 256, 0, stream>>>(x, n1w, n1b, bufX);

  // QKV GEMM + window attention, chunked over images.
  for (int i0 = 0; i0 < B_; i0 += ic) {
    const int nbm = ic * 3136 / 256, nbn = 6;
    gemm_bt<0><<<nbm * nbn, 512, 0, stream>>>(
        bufX + (size_t)i0*3136*512, wqB, qkvb, nullptr, R, 1536, 512, 512, nbn);
    attn_win2<<<ic*64*2, 512, 0, stream>>>(R, biasBf, bufX, i0);
  }

  // proj GEMM + residual(x) -> d_out (f32)  [= x1]
  gemm_bt<2><<<(ROWS/256) * 2, 512, 0, stream>>>(
      bufX, wpB, projb, x, out, 512, 512, 512, 2);

  // LN2 -> bf16
  ln_bf16<<<ROWS/4, 256, 0, stream>>>(out, n2w, n2b, bufX);

  // MLP, chunked over hidden dim. FC2 accumulates into out (bias in chunk 0).
  for (int h0 = 0; h0 < 2048; h0 += hc) {
    gemm_bt<1><<<(ROWS/256) * (hc/256), 512, 0, stream>>>(
        bufX, w1B + (size_t)h0*512, fc1b + h0, nullptr, R, hc, 512, 512, hc/256);
    if (h0 == 0)
      gemm_bt<2><<<(ROWS/256) * 2, 512, 0, stream>>>(
          R, w2B + h0, fc2b, out, out, 512, hc, 2048, 2);
    else
      gemm_bt<3><<<(ROWS/256) * 2, 512, 0, stream>>>(
          R, w2B + h0, nullptr, out, out, 512, hc, 2048, 2);
  }
}